// Round 12
// baseline (506.032 us; speedup 1.0000x reference)
//
#include <hip/hip_runtime.h>

#define NN 50000
#define NE 800000
#define NG 128
#define NC 41
#define CAP 64
#define XG 8            // XCD groups for fill partitioning
#define RNG 6250        // NN / XG

typedef __attribute__((ext_vector_type(8))) short bfrag8;
typedef __attribute__((ext_vector_type(4))) float facc4;

__device__ __forceinline__ float bf2f(unsigned short u) {
  union { unsigned int i; float f; } v; v.i = ((unsigned int)u) << 16; return v.f;
}
__device__ __forceinline__ unsigned short f2bf(float f) {
  union { float f; unsigned int i; } v; v.f = f;
  unsigned int x = v.i;
  x += 0x7fffu + ((x >> 16) & 1u);
  return (unsigned short)(x >> 16);
}
__device__ __forceinline__ void acc_u4(const uint4 u, float* a) {
  union { unsigned int i; float f; } c;
  c.i = u.x << 16;          a[0] += c.f;
  c.i = u.x & 0xffff0000u;  a[1] += c.f;
  c.i = u.y << 16;          a[2] += c.f;
  c.i = u.y & 0xffff0000u;  a[3] += c.f;
  c.i = u.z << 16;          a[4] += c.f;
  c.i = u.z & 0xffff0000u;  a[5] += c.f;
  c.i = u.w << 16;          a[6] += c.f;
  c.i = u.w & 0xffff0000u;  a[7] += c.f;
}
__device__ __forceinline__ unsigned int pack2(float lo, float hi) {
  return (unsigned int)f2bf(lo) | ((unsigned int)f2bf(hi) << 16);
}

// Weights -> bf16, BN affine precompute (applied AFTER relu).
__global__ void prep_kernel(const float* __restrict__ W1, const float* __restrict__ W2,
                            const float* __restrict__ oW1, const float* __restrict__ oW2,
                            const float* __restrict__ gamma, const float* __restrict__ beta,
                            const float* __restrict__ mean, const float* __restrict__ var,
                            unsigned short* W1b, unsigned short* W2b,
                            unsigned short* oW1b, unsigned short* oW2b,
                            float* scale, float* shift) {
  int i = blockIdx.x * 256 + threadIdx.x;
  if (i < 128 * 128) {
    W1b[i] = f2bf(W1[i]);
    W2b[i] = f2bf(W2[i]);
    oW1b[i] = f2bf(oW1[i]);
    oW2b[i] = f2bf(oW2[i]);
  }
  if (i < 128) {
    float s = gamma[i] * rsqrtf(var[i] + 1e-5f);
    scale[i] = s;
    shift[i] = beta[i] - mean[i] * s;
  }
}

// x = emb[node_ids], stored bf16. One thread per 4 feats.
__global__ void embed_kernel(const int* __restrict__ node_ids, const float* __restrict__ emb,
                             unsigned short* __restrict__ xb) {
  int idx = blockIdx.x * 256 + threadIdx.x;
  if (idx >= NN * 32) return;
  int node = idx >> 5, f = (idx & 31) * 4;
  const float4 v = *(const float4*)&emb[node_ids[node] * 128 + f];
  ushort4 o;
  o.x = f2bf(v.x); o.y = f2bf(v.y); o.z = f2bf(v.z); o.w = f2bf(v.w);
  *(ushort4*)&xb[node * 128 + f] = o;
}

// XCD-partitioned edge bucketing (r11-validated): block b -> group g=b&7,
// chunk s=b>>3; group g commits only dst in [g*RNG,(g+1)*RNG).
__global__ __launch_bounds__(256) void fill_kernel(const int* __restrict__ ei,
                                                   int* __restrict__ cnt,
                                                   unsigned short* __restrict__ srclist) {
  int b = blockIdx.x;
  int g = b & 7;
  int s = b >> 3;
  int e = s * 256 + threadIdx.x;
  if (e >= NE) return;
  int d = ei[NE + e];
  unsigned int lo = g * RNG;
  if ((unsigned int)(d - lo) < (unsigned int)RNG) {
    int src = ei[e];
    int pos = atomicAdd(&cnt[d], 1);
    if (pos < CAP) srclist[d * CAP + pos] = (unsigned short)src;
  }
}

// h = x + sum_{neighbors} x. 16 nodes/block, 16 lanes/node, 16B loads, unroll 8/4/1.
// (r5-validated structure; srclist ushort)
__global__ __launch_bounds__(256) void agg_kernel(const unsigned short* __restrict__ xb,
                                                  const int* __restrict__ cnt,
                                                  const unsigned short* __restrict__ srclist,
                                                  unsigned short* __restrict__ hb) {
  int tid = threadIdx.x;
  int node = blockIdx.x * 16 + (tid >> 4);
  if (node >= NN) return;
  int f = (tid & 15) * 8;
  float a[8];
  acc_u4(*(const uint4*)&xb[node * 128 + f],
         (a[0]=0.f, a[1]=0.f, a[2]=0.f, a[3]=0.f, a[4]=0.f, a[5]=0.f, a[6]=0.f, a[7]=0.f, a));
  int deg = cnt[node];
  if (deg > CAP) deg = CAP;
  const unsigned short* lst = &srclist[node * CAP];
  int j = 0;
  for (; j + 8 <= deg; j += 8) {
    uint4 u0 = *(const uint4*)&xb[(int)lst[j] * 128 + f];
    uint4 u1 = *(const uint4*)&xb[(int)lst[j + 1] * 128 + f];
    uint4 u2 = *(const uint4*)&xb[(int)lst[j + 2] * 128 + f];
    uint4 u3 = *(const uint4*)&xb[(int)lst[j + 3] * 128 + f];
    uint4 u4 = *(const uint4*)&xb[(int)lst[j + 4] * 128 + f];
    uint4 u5 = *(const uint4*)&xb[(int)lst[j + 5] * 128 + f];
    uint4 u6 = *(const uint4*)&xb[(int)lst[j + 6] * 128 + f];
    uint4 u7 = *(const uint4*)&xb[(int)lst[j + 7] * 128 + f];
    acc_u4(u0, a); acc_u4(u1, a); acc_u4(u2, a); acc_u4(u3, a);
    acc_u4(u4, a); acc_u4(u5, a); acc_u4(u6, a); acc_u4(u7, a);
  }
  for (; j + 4 <= deg; j += 4) {
    uint4 u0 = *(const uint4*)&xb[(int)lst[j] * 128 + f];
    uint4 u1 = *(const uint4*)&xb[(int)lst[j + 1] * 128 + f];
    uint4 u2 = *(const uint4*)&xb[(int)lst[j + 2] * 128 + f];
    uint4 u3 = *(const uint4*)&xb[(int)lst[j + 3] * 128 + f];
    acc_u4(u0, a); acc_u4(u1, a); acc_u4(u2, a); acc_u4(u3, a);
  }
  for (; j < deg; ++j) {
    uint4 u = *(const uint4*)&xb[(int)lst[j] * 128 + f];
    acc_u4(u, a);
  }
  uint4 o;
  o.x = pack2(a[0], a[1]); o.y = pack2(a[2], a[3]);
  o.z = pack2(a[4], a[5]); o.w = pack2(a[6], a[7]);
  *(uint4*)&hb[node * 128 + f] = o;
}

// Fused MLP (64-row tile, 256 thr, 48KB LDS -> 3 blocks/CU, r10-validated).
// NEW: W2 prefetched into registers at entry (latency hidden behind W1 staging
// + GEMM1); mid-kernel restage is pure ds_write, removing global latency from
// the per-block serial chain.
__global__ __launch_bounds__(256, 3) void mlp_kernel(const unsigned short* __restrict__ A,
                                                     const unsigned short* __restrict__ W1b,
                                                     const unsigned short* __restrict__ W2b,
                                                     const float* __restrict__ bias1,
                                                     const float* __restrict__ bias2,
                                                     const float* __restrict__ scale,
                                                     const float* __restrict__ shift,
                                                     unsigned short* __restrict__ Out,
                                                     int M, int mode) {
  __shared__ unsigned short sW[128 * 128];   // 32KB: W1, then W2
  __shared__ unsigned short sA[64 * 128];    // 16KB
  int tid = threadIdx.x;
  int bRow = blockIdx.x * 64;

  // prefetch W2 into registers (8 x uint4 per thread)
  const uint4* gw2 = (const uint4*)W2b;
  uint4 w2r[8];
#pragma unroll
  for (int p = 0; p < 8; ++p) w2r[p] = gw2[p * 256 + tid];

  const uint4* gw1 = (const uint4*)W1b;
#pragma unroll
  for (int p = 0; p < 8; ++p) {
    int g = p * 256 + tid;
    int r = g >> 4, b = g & 15;
    int ph = (b + r) & 15;
    *(uint4*)&sW[(r * 16 + ph) * 8] = gw1[g];
  }
#pragma unroll
  for (int p = 0; p < 4; ++p) {
    int g = p * 256 + tid;
    int r = g >> 4, b = g & 15;
    int ph = (b + r) & 15;
    int grow = bRow + r;
    uint4 v = {0u, 0u, 0u, 0u};
    if (grow < M) v = *(const uint4*)&A[grow * 128 + b * 8];
    *(uint4*)&sA[(r * 16 + ph) * 8] = v;
  }
  __syncthreads();

  int wave = tid >> 6;
  int lane = tid & 63;
  int l16 = lane & 15;
  int quad = lane >> 4;
  int arow = wave * 16 + l16;

  // ---- GEMM1: T = relu(A @ W1^T + b1), T overwrites own stripe of sA ----
  {
    bfrag8 af[4];
#pragma unroll
    for (int k = 0; k < 4; ++k) {
      int ph = (k * 4 + quad + arow) & 15;
      af[k] = *(const bfrag8*)&sA[(arow * 16 + ph) * 8];
    }
    facc4 acc[8];
#pragma unroll
    for (int t = 0; t < 8; ++t) acc[t] = (facc4){0.f, 0.f, 0.f, 0.f};
#pragma unroll
    for (int k = 0; k < 4; ++k) {
#pragma unroll
      for (int t = 0; t < 8; ++t) {
        int r = t * 16 + l16;
        int ph = (k * 4 + quad + r) & 15;
        bfrag8 bf = *(const bfrag8*)&sW[(r * 16 + ph) * 8];
        acc[t] = __builtin_amdgcn_mfma_f32_16x16x32_bf16(af[k], bf, acc[t], 0, 0, 0);
      }
    }
#pragma unroll
    for (int t = 0; t < 8; ++t) {
      int col = t * 16 + l16;
      float b = bias1[col];
      int cb = col >> 3, ce = col & 7;
#pragma unroll
      for (int i = 0; i < 4; ++i) {
        int row = wave * 16 + quad * 4 + i;
        float v = acc[t][i] + b;
        int ph = (cb + row) & 15;
        sA[(row * 16 + ph) * 8 + ce] = f2bf(v > 0.f ? v : 0.f);
      }
    }
  }
  __syncthreads();   // all W1 reads done before restage

  // ---- restage W2 from registers (no global latency) ----
#pragma unroll
  for (int p = 0; p < 8; ++p) {
    int g = p * 256 + tid;
    int r = g >> 4, b = g & 15;
    int ph = (b + r) & 15;
    *(uint4*)&sW[(r * 16 + ph) * 8] = w2r[p];
  }
  __syncthreads();   // W2 staged before GEMM2 reads

  // ---- GEMM2: Out = ep2(T @ W2^T + b2), epilogue back into own stripe ----
  {
    bfrag8 af[4];
#pragma unroll
    for (int k = 0; k < 4; ++k) {
      int ph = (k * 4 + quad + arow) & 15;
      af[k] = *(const bfrag8*)&sA[(arow * 16 + ph) * 8];
    }
    facc4 acc[8];
#pragma unroll
    for (int t = 0; t < 8; ++t) acc[t] = (facc4){0.f, 0.f, 0.f, 0.f};
#pragma unroll
    for (int k = 0; k < 4; ++k) {
#pragma unroll
      for (int t = 0; t < 8; ++t) {
        int r = t * 16 + l16;
        int ph = (k * 4 + quad + r) & 15;
        bfrag8 bf = *(const bfrag8*)&sW[(r * 16 + ph) * 8];
        acc[t] = __builtin_amdgcn_mfma_f32_16x16x32_bf16(af[k], bf, acc[t], 0, 0, 0);
      }
    }
#pragma unroll
    for (int t = 0; t < 8; ++t) {
      int col = t * 16 + l16;
      float b = bias2[col];
      float sc = 1.f, sh = 0.f;
      if (mode == 1) { sc = scale[col]; sh = shift[col]; }
      int cb = col >> 3, ce = col & 7;
#pragma unroll
      for (int i = 0; i < 4; ++i) {
        int row = wave * 16 + quad * 4 + i;
        float v = acc[t][i] + b;
        v = v > 0.f ? v : 0.f;
        if (mode == 1) v = v * sc + sh;
        int ph = (cb + row) & 15;
        sA[(row * 16 + ph) * 8 + ce] = f2bf(v);
      }
    }
  }
  __syncthreads();

#pragma unroll
  for (int p = 0; p < 4; ++p) {
    int g = p * 256 + tid;
    int r = g >> 4, b = g & 15;
    int ph = (b + r) & 15;
    int grow = bRow + r;
    if (grow < M)
      *(uint4*)&Out[grow * 128 + b * 8] = *(const uint4*)&sA[(r * 16 + ph) * 8];
  }
}

// pooled[g, f] += sum over contiguous nodes with batch==g (batch sorted)
__global__ __launch_bounds__(128) void pool_kernel(const unsigned short* __restrict__ xb,
                                                   const int* __restrict__ batch,
                                                   float* __restrict__ pooled) {
  const int CHUNK = 128;
  int start = blockIdx.x * CHUNK;
  int end = start + CHUNK;
  if (end > NN) end = NN;
  int f = threadIdx.x;
  float acc = 0.f;
  int cur = -1;
  for (int i = start; i < end; ++i) {
    int b = batch[i];
    if (b != cur) {
      if (cur >= 0) atomicAdd(&pooled[cur * 128 + f], acc);
      cur = b;
      acc = 0.f;
    }
    acc += bf2f(xb[i * 128 + f]);
  }
  if (cur >= 0) atomicAdd(&pooled[cur * 128 + f], acc);
}

// Fused head: h1 = relu(pooled[r]@fc1_W^T+b1) in LDS, then out[r] = h1@fc2_W^T+b2.
__global__ __launch_bounds__(128) void fc_kernel(const float* __restrict__ pooled,
                                                 const float* __restrict__ W1,
                                                 const float* __restrict__ b1,
                                                 const float* __restrict__ W2,
                                                 const float* __restrict__ b2,
                                                 float* __restrict__ out) {
  __shared__ float sh1[128];
  __shared__ float sp[128];
  int r = blockIdx.x;
  int c = threadIdx.x;
  sp[c] = pooled[r * 128 + c];
  __syncthreads();
  float acc = 0.f;
  for (int k = 0; k < 128; ++k) acc += sp[k] * W1[c * 128 + k];
  acc += b1[c];
  sh1[c] = acc > 0.f ? acc : 0.f;
  __syncthreads();
  if (c < NC) {
    float o = 0.f;
    for (int k = 0; k < 128; ++k) o += sh1[k] * W2[c * 128 + k];
    out[r * NC + c] = o + b2[c];
  }
}

extern "C" void kernel_launch(void* const* d_in, const int* in_sizes, int n_in,
                              void* d_out, int out_size, void* d_ws, size_t ws_size,
                              hipStream_t stream) {
  const int* node_ids = (const int*)d_in[0];
  const int* edge_index = (const int*)d_in[1];
  const int* batch = (const int*)d_in[2];
  const float* emb = (const float*)d_in[3];
  const float* in_W1 = (const float*)d_in[4];
  const float* in_b1 = (const float*)d_in[5];
  const float* in_W2 = (const float*)d_in[6];
  const float* in_b2 = (const float*)d_in[7];
  const float* bn_gamma = (const float*)d_in[8];
  const float* bn_beta = (const float*)d_in[9];
  const float* bn_mean = (const float*)d_in[10];
  const float* bn_var = (const float*)d_in[11];
  const float* out_W1 = (const float*)d_in[12];
  const float* out_b1 = (const float*)d_in[13];
  const float* out_W2 = (const float*)d_in[14];
  const float* out_b2 = (const float*)d_in[15];
  const float* fc1_W = (const float*)d_in[16];
  const float* fc1_b = (const float*)d_in[17];
  const float* fc2_W = (const float*)d_in[18];
  const float* fc2_b = (const float*)d_in[19];
  float* out = (float*)d_out;

  char* ws = (char*)d_ws;
  size_t off = 0;
  auto alloc = [&](size_t bytes) {
    char* p = ws + off;
    off = (off + bytes + 255) & ~(size_t)255;
    return p;
  };
  unsigned short* xb = (unsigned short*)alloc((size_t)NN * 128 * 2);
  unsigned short* hb = (unsigned short*)alloc((size_t)NN * 128 * 2);
  unsigned short* srclist = (unsigned short*)alloc((size_t)NN * CAP * 2);
  int* cnt = (int*)alloc((size_t)NN * 4);
  unsigned short* W1b = (unsigned short*)alloc(128 * 128 * 2);
  unsigned short* W2b = (unsigned short*)alloc(128 * 128 * 2);
  unsigned short* oW1b = (unsigned short*)alloc(128 * 128 * 2);
  unsigned short* oW2b = (unsigned short*)alloc(128 * 128 * 2);
  float* bnscale = (float*)alloc(128 * 4);
  float* bnshift = (float*)alloc(128 * 4);
  float* pooled = (float*)alloc(NG * 128 * 4);

  hipMemsetAsync(cnt, 0, (size_t)NN * 4, stream);
  hipMemsetAsync(pooled, 0, (size_t)NG * 128 * 4, stream);

  prep_kernel<<<64, 256, 0, stream>>>(in_W1, in_W2, out_W1, out_W2,
                                      bn_gamma, bn_beta, bn_mean, bn_var,
                                      W1b, W2b, oW1b, oW2b, bnscale, bnshift);
  int chunks = (NE + 255) / 256;
  fill_kernel<<<chunks * XG, 256, 0, stream>>>(edge_index, cnt, srclist);
  embed_kernel<<<(NN * 32 + 255) / 256, 256, 0, stream>>>(node_ids, emb, xb);

  int mlp_blocks = (NN + 63) / 64;
  for (int l = 0; l < 6; ++l) {
    const unsigned short* w1 = (l < 5) ? W1b : oW1b;
    const unsigned short* w2 = (l < 5) ? W2b : oW2b;
    const float* b1 = (l < 5) ? in_b1 : out_b1;
    const float* b2 = (l < 5) ? in_b2 : out_b2;
    int mode2 = (l < 5) ? 1 : 0;
    agg_kernel<<<(NN + 15) / 16, 256, 0, stream>>>(xb, cnt, srclist, hb);
    mlp_kernel<<<mlp_blocks, 256, 0, stream>>>(hb, w1, w2, b1, b2, bnscale, bnshift,
                                               xb, NN, mode2);
  }

  pool_kernel<<<(NN + 127) / 128, 128, 0, stream>>>(xb, batch, pooled);
  fc_kernel<<<NG, 128, 0, stream>>>(pooled, fc1_W, fc1_b, fc2_W, fc2_b, out);
}

// Round 13
// 492.690 us; speedup vs baseline: 1.0271x; 1.0271x over previous
//
#include <hip/hip_runtime.h>

#define NN 50000
#define NE 800000
#define NG 128
#define NC 41
#define CAP 64
#define XG 8            // XCD groups for fill partitioning
#define RNG 6250        // NN / XG

typedef __attribute__((ext_vector_type(8))) short bfrag8;
typedef __attribute__((ext_vector_type(4))) float facc4;

__device__ __forceinline__ float bf2f(unsigned short u) {
  union { unsigned int i; float f; } v; v.i = ((unsigned int)u) << 16; return v.f;
}
__device__ __forceinline__ unsigned short f2bf(float f) {
  union { float f; unsigned int i; } v; v.f = f;
  unsigned int x = v.i;
  x += 0x7fffu + ((x >> 16) & 1u);
  return (unsigned short)(x >> 16);
}
__device__ __forceinline__ void acc_u4(const uint4 u, float* a) {
  union { unsigned int i; float f; } c;
  c.i = u.x << 16;          a[0] += c.f;
  c.i = u.x & 0xffff0000u;  a[1] += c.f;
  c.i = u.y << 16;          a[2] += c.f;
  c.i = u.y & 0xffff0000u;  a[3] += c.f;
  c.i = u.z << 16;          a[4] += c.f;
  c.i = u.z & 0xffff0000u;  a[5] += c.f;
  c.i = u.w << 16;          a[6] += c.f;
  c.i = u.w & 0xffff0000u;  a[7] += c.f;
}
__device__ __forceinline__ unsigned int pack2(float lo, float hi) {
  return (unsigned int)f2bf(lo) | ((unsigned int)f2bf(hi) << 16);
}

// Weights -> bf16, BN affine precompute (applied AFTER relu).
__global__ void prep_kernel(const float* __restrict__ W1, const float* __restrict__ W2,
                            const float* __restrict__ oW1, const float* __restrict__ oW2,
                            const float* __restrict__ gamma, const float* __restrict__ beta,
                            const float* __restrict__ mean, const float* __restrict__ var,
                            unsigned short* W1b, unsigned short* W2b,
                            unsigned short* oW1b, unsigned short* oW2b,
                            float* scale, float* shift) {
  int i = blockIdx.x * 256 + threadIdx.x;
  if (i < 128 * 128) {
    W1b[i] = f2bf(W1[i]);
    W2b[i] = f2bf(W2[i]);
    oW1b[i] = f2bf(oW1[i]);
    oW2b[i] = f2bf(oW2[i]);
  }
  if (i < 128) {
    float s = gamma[i] * rsqrtf(var[i] + 1e-5f);
    scale[i] = s;
    shift[i] = beta[i] - mean[i] * s;
  }
}

// x = emb[node_ids], stored bf16. One thread per 4 feats.
__global__ void embed_kernel(const int* __restrict__ node_ids, const float* __restrict__ emb,
                             unsigned short* __restrict__ xb) {
  int idx = blockIdx.x * 256 + threadIdx.x;
  if (idx >= NN * 32) return;
  int node = idx >> 5, f = (idx & 31) * 4;
  const float4 v = *(const float4*)&emb[node_ids[node] * 128 + f];
  ushort4 o;
  o.x = f2bf(v.x); o.y = f2bf(v.y); o.z = f2bf(v.z); o.w = f2bf(v.w);
  *(ushort4*)&xb[node * 128 + f] = o;
}

// XCD-partitioned edge bucketing (r11-validated): block b -> group g=b&7,
// chunk s=b>>3; group g commits only dst in [g*RNG,(g+1)*RNG) -> srclist/cnt
// slices stay L2-local per XCD (kills cross-XCD 64B-line ping-pong).
__global__ __launch_bounds__(256) void fill_kernel(const int* __restrict__ ei,
                                                   int* __restrict__ cnt,
                                                   unsigned short* __restrict__ srclist) {
  int b = blockIdx.x;
  int g = b & 7;
  int s = b >> 3;
  int e = s * 256 + threadIdx.x;
  if (e >= NE) return;
  int d = ei[NE + e];
  unsigned int lo = g * RNG;
  if ((unsigned int)(d - lo) < (unsigned int)RNG) {
    int src = ei[e];
    int pos = atomicAdd(&cnt[d], 1);
    if (pos < CAP) srclist[d * CAP + pos] = (unsigned short)src;
  }
}

// h = x + sum_{neighbors} x. 16 nodes/block, 16 lanes/node, 16B loads, unroll 8/4/1.
// (r5-validated structure; srclist ushort)
__global__ __launch_bounds__(256) void agg_kernel(const unsigned short* __restrict__ xb,
                                                  const int* __restrict__ cnt,
                                                  const unsigned short* __restrict__ srclist,
                                                  unsigned short* __restrict__ hb) {
  int tid = threadIdx.x;
  int node = blockIdx.x * 16 + (tid >> 4);
  if (node >= NN) return;
  int f = (tid & 15) * 8;
  float a[8];
  acc_u4(*(const uint4*)&xb[node * 128 + f],
         (a[0]=0.f, a[1]=0.f, a[2]=0.f, a[3]=0.f, a[4]=0.f, a[5]=0.f, a[6]=0.f, a[7]=0.f, a));
  int deg = cnt[node];
  if (deg > CAP) deg = CAP;
  const unsigned short* lst = &srclist[node * CAP];
  int j = 0;
  for (; j + 8 <= deg; j += 8) {
    uint4 u0 = *(const uint4*)&xb[(int)lst[j] * 128 + f];
    uint4 u1 = *(const uint4*)&xb[(int)lst[j + 1] * 128 + f];
    uint4 u2 = *(const uint4*)&xb[(int)lst[j + 2] * 128 + f];
    uint4 u3 = *(const uint4*)&xb[(int)lst[j + 3] * 128 + f];
    uint4 u4 = *(const uint4*)&xb[(int)lst[j + 4] * 128 + f];
    uint4 u5 = *(const uint4*)&xb[(int)lst[j + 5] * 128 + f];
    uint4 u6 = *(const uint4*)&xb[(int)lst[j + 6] * 128 + f];
    uint4 u7 = *(const uint4*)&xb[(int)lst[j + 7] * 128 + f];
    acc_u4(u0, a); acc_u4(u1, a); acc_u4(u2, a); acc_u4(u3, a);
    acc_u4(u4, a); acc_u4(u5, a); acc_u4(u6, a); acc_u4(u7, a);
  }
  for (; j + 4 <= deg; j += 4) {
    uint4 u0 = *(const uint4*)&xb[(int)lst[j] * 128 + f];
    uint4 u1 = *(const uint4*)&xb[(int)lst[j + 1] * 128 + f];
    uint4 u2 = *(const uint4*)&xb[(int)lst[j + 2] * 128 + f];
    uint4 u3 = *(const uint4*)&xb[(int)lst[j + 3] * 128 + f];
    acc_u4(u0, a); acc_u4(u1, a); acc_u4(u2, a); acc_u4(u3, a);
  }
  for (; j < deg; ++j) {
    uint4 u = *(const uint4*)&xb[(int)lst[j] * 128 + f];
    acc_u4(u, a);
  }
  uint4 o;
  o.x = pack2(a[0], a[1]); o.y = pack2(a[2], a[3]);
  o.z = pack2(a[4], a[5]); o.w = pack2(a[6], a[7]);
  *(uint4*)&hb[node * 128 + f] = o;
}

// Fused MLP: Out = ep2(relu(A@W1^T+b1) @ W2^T + b2) for a 64-row tile.
// 256 threads, 48KB LDS -> 3 blocks/CU (r10/r11-validated best).
// sW holds W1 during GEMM1, restaged with W2 between GEMMs (barriers).
// XOR-16B-chunk swizzle; wave-private no-sT handoff (r7-validated).
__global__ __launch_bounds__(256) void mlp_kernel(const unsigned short* __restrict__ A,
                                                  const unsigned short* __restrict__ W1b,
                                                  const unsigned short* __restrict__ W2b,
                                                  const float* __restrict__ bias1,
                                                  const float* __restrict__ bias2,
                                                  const float* __restrict__ scale,
                                                  const float* __restrict__ shift,
                                                  unsigned short* __restrict__ Out,
                                                  int M, int mode) {
  __shared__ unsigned short sW[128 * 128];   // 32KB: W1, then W2
  __shared__ unsigned short sA[64 * 128];    // 16KB
  int tid = threadIdx.x;
  int bRow = blockIdx.x * 64;

  const uint4* gw1 = (const uint4*)W1b;
#pragma unroll
  for (int p = 0; p < 8; ++p) {
    int g = p * 256 + tid;
    int r = g >> 4, b = g & 15;
    int ph = (b + r) & 15;
    *(uint4*)&sW[(r * 16 + ph) * 8] = gw1[g];
  }
#pragma unroll
  for (int p = 0; p < 4; ++p) {
    int g = p * 256 + tid;
    int r = g >> 4, b = g & 15;
    int ph = (b + r) & 15;
    int grow = bRow + r;
    uint4 v = {0u, 0u, 0u, 0u};
    if (grow < M) v = *(const uint4*)&A[grow * 128 + b * 8];
    *(uint4*)&sA[(r * 16 + ph) * 8] = v;
  }
  __syncthreads();

  int wave = tid >> 6;
  int lane = tid & 63;
  int l16 = lane & 15;
  int quad = lane >> 4;
  int arow = wave * 16 + l16;

  // ---- GEMM1 ----
  {
    bfrag8 af[4];
#pragma unroll
    for (int k = 0; k < 4; ++k) {
      int ph = (k * 4 + quad + arow) & 15;
      af[k] = *(const bfrag8*)&sA[(arow * 16 + ph) * 8];
    }
    facc4 acc[8];
#pragma unroll
    for (int t = 0; t < 8; ++t) acc[t] = (facc4){0.f, 0.f, 0.f, 0.f};
#pragma unroll
    for (int k = 0; k < 4; ++k) {
#pragma unroll
      for (int t = 0; t < 8; ++t) {
        int r = t * 16 + l16;
        int ph = (k * 4 + quad + r) & 15;
        bfrag8 bf = *(const bfrag8*)&sW[(r * 16 + ph) * 8];
        acc[t] = __builtin_amdgcn_mfma_f32_16x16x32_bf16(af[k], bf, acc[t], 0, 0, 0);
      }
    }
#pragma unroll
    for (int t = 0; t < 8; ++t) {
      int col = t * 16 + l16;
      float b = bias1[col];
      int cb = col >> 3, ce = col & 7;
#pragma unroll
      for (int i = 0; i < 4; ++i) {
        int row = wave * 16 + quad * 4 + i;
        float v = acc[t][i] + b;
        int ph = (cb + row) & 15;
        sA[(row * 16 + ph) * 8 + ce] = f2bf(v > 0.f ? v : 0.f);
      }
    }
  }
  __syncthreads();   // all W1 reads done before restage

  const uint4* gw2 = (const uint4*)W2b;
#pragma unroll
  for (int p = 0; p < 8; ++p) {
    int g = p * 256 + tid;
    int r = g >> 4, b = g & 15;
    int ph = (b + r) & 15;
    *(uint4*)&sW[(r * 16 + ph) * 8] = gw2[g];
  }
  __syncthreads();   // W2 staged before GEMM2 reads

  // ---- GEMM2 ----
  {
    bfrag8 af[4];
#pragma unroll
    for (int k = 0; k < 4; ++k) {
      int ph = (k * 4 + quad + arow) & 15;
      af[k] = *(const bfrag8*)&sA[(arow * 16 + ph) * 8];
    }
    facc4 acc[8];
#pragma unroll
    for (int t = 0; t < 8; ++t) acc[t] = (facc4){0.f, 0.f, 0.f, 0.f};
#pragma unroll
    for (int k = 0; k < 4; ++k) {
#pragma unroll
      for (int t = 0; t < 8; ++t) {
        int r = t * 16 + l16;
        int ph = (k * 4 + quad + r) & 15;
        bfrag8 bf = *(const bfrag8*)&sW[(r * 16 + ph) * 8];
        acc[t] = __builtin_amdgcn_mfma_f32_16x16x32_bf16(af[k], bf, acc[t], 0, 0, 0);
      }
    }
#pragma unroll
    for (int t = 0; t < 8; ++t) {
      int col = t * 16 + l16;
      float b = bias2[col];
      float sc = 1.f, sh = 0.f;
      if (mode == 1) { sc = scale[col]; sh = shift[col]; }
      int cb = col >> 3, ce = col & 7;
#pragma unroll
      for (int i = 0; i < 4; ++i) {
        int row = wave * 16 + quad * 4 + i;
        float v = acc[t][i] + b;
        v = v > 0.f ? v : 0.f;
        if (mode == 1) v = v * sc + sh;
        int ph = (cb + row) & 15;
        sA[(row * 16 + ph) * 8 + ce] = f2bf(v);
      }
    }
  }
  __syncthreads();

#pragma unroll
  for (int p = 0; p < 4; ++p) {
    int g = p * 256 + tid;
    int r = g >> 4, b = g & 15;
    int ph = (b + r) & 15;
    int grow = bRow + r;
    if (grow < M)
      *(uint4*)&Out[grow * 128 + b * 8] = *(const uint4*)&sA[(r * 16 + ph) * 8];
  }
}

// pooled[g, f] += sum over contiguous nodes with batch==g (batch sorted)
__global__ __launch_bounds__(128) void pool_kernel(const unsigned short* __restrict__ xb,
                                                   const int* __restrict__ batch,
                                                   float* __restrict__ pooled) {
  const int CHUNK = 128;
  int start = blockIdx.x * CHUNK;
  int end = start + CHUNK;
  if (end > NN) end = NN;
  int f = threadIdx.x;
  float acc = 0.f;
  int cur = -1;
  for (int i = start; i < end; ++i) {
    int b = batch[i];
    if (b != cur) {
      if (cur >= 0) atomicAdd(&pooled[cur * 128 + f], acc);
      cur = b;
      acc = 0.f;
    }
    acc += bf2f(xb[i * 128 + f]);
  }
  if (cur >= 0) atomicAdd(&pooled[cur * 128 + f], acc);
}

// Fused head: h1 = relu(pooled[r]@fc1_W^T+b1) in LDS, then out[r] = h1@fc2_W^T+b2.
__global__ __launch_bounds__(128) void fc_kernel(const float* __restrict__ pooled,
                                                 const float* __restrict__ W1,
                                                 const float* __restrict__ b1,
                                                 const float* __restrict__ W2,
                                                 const float* __restrict__ b2,
                                                 float* __restrict__ out) {
  __shared__ float sh1[128];
  __shared__ float sp[128];
  int r = blockIdx.x;
  int c = threadIdx.x;
  sp[c] = pooled[r * 128 + c];
  __syncthreads();
  float acc = 0.f;
  for (int k = 0; k < 128; ++k) acc += sp[k] * W1[c * 128 + k];
  acc += b1[c];
  sh1[c] = acc > 0.f ? acc : 0.f;
  __syncthreads();
  if (c < NC) {
    float o = 0.f;
    for (int k = 0; k < 128; ++k) o += sh1[k] * W2[c * 128 + k];
    out[r * NC + c] = o + b2[c];
  }
}

extern "C" void kernel_launch(void* const* d_in, const int* in_sizes, int n_in,
                              void* d_out, int out_size, void* d_ws, size_t ws_size,
                              hipStream_t stream) {
  const int* node_ids = (const int*)d_in[0];
  const int* edge_index = (const int*)d_in[1];
  const int* batch = (const int*)d_in[2];
  const float* emb = (const float*)d_in[3];
  const float* in_W1 = (const float*)d_in[4];
  const float* in_b1 = (const float*)d_in[5];
  const float* in_W2 = (const float*)d_in[6];
  const float* in_b2 = (const float*)d_in[7];
  const float* bn_gamma = (const float*)d_in[8];
  const float* bn_beta = (const float*)d_in[9];
  const float* bn_mean = (const float*)d_in[10];
  const float* bn_var = (const float*)d_in[11];
  const float* out_W1 = (const float*)d_in[12];
  const float* out_b1 = (const float*)d_in[13];
  const float* out_W2 = (const float*)d_in[14];
  const float* out_b2 = (const float*)d_in[15];
  const float* fc1_W = (const float*)d_in[16];
  const float* fc1_b = (const float*)d_in[17];
  const float* fc2_W = (const float*)d_in[18];
  const float* fc2_b = (const float*)d_in[19];
  float* out = (float*)d_out;

  char* ws = (char*)d_ws;
  size_t off = 0;
  auto alloc = [&](size_t bytes) {
    char* p = ws + off;
    off = (off + bytes + 255) & ~(size_t)255;
    return p;
  };
  unsigned short* xb = (unsigned short*)alloc((size_t)NN * 128 * 2);
  unsigned short* hb = (unsigned short*)alloc((size_t)NN * 128 * 2);
  unsigned short* srclist = (unsigned short*)alloc((size_t)NN * CAP * 2);
  int* cnt = (int*)alloc((size_t)NN * 4);
  unsigned short* W1b = (unsigned short*)alloc(128 * 128 * 2);
  unsigned short* W2b = (unsigned short*)alloc(128 * 128 * 2);
  unsigned short* oW1b = (unsigned short*)alloc(128 * 128 * 2);
  unsigned short* oW2b = (unsigned short*)alloc(128 * 128 * 2);
  float* bnscale = (float*)alloc(128 * 4);
  float* bnshift = (float*)alloc(128 * 4);
  float* pooled = (float*)alloc(NG * 128 * 4);

  hipMemsetAsync(cnt, 0, (size_t)NN * 4, stream);
  hipMemsetAsync(pooled, 0, (size_t)NG * 128 * 4, stream);

  prep_kernel<<<64, 256, 0, stream>>>(in_W1, in_W2, out_W1, out_W2,
                                      bn_gamma, bn_beta, bn_mean, bn_var,
                                      W1b, W2b, oW1b, oW2b, bnscale, bnshift);
  int chunks = (NE + 255) / 256;
  fill_kernel<<<chunks * XG, 256, 0, stream>>>(edge_index, cnt, srclist);
  embed_kernel<<<(NN * 32 + 255) / 256, 256, 0, stream>>>(node_ids, emb, xb);

  int mlp_blocks = (NN + 63) / 64;
  for (int l = 0; l < 6; ++l) {
    const unsigned short* w1 = (l < 5) ? W1b : oW1b;
    const unsigned short* w2 = (l < 5) ? W2b : oW2b;
    const float* b1 = (l < 5) ? in_b1 : out_b1;
    const float* b2 = (l < 5) ? in_b2 : out_b2;
    int mode2 = (l < 5) ? 1 : 0;
    agg_kernel<<<(NN + 15) / 16, 256, 0, stream>>>(xb, cnt, srclist, hb);
    mlp_kernel<<<mlp_blocks, 256, 0, stream>>>(hb, w1, w2, b1, b2, bnscale, bnshift,
                                               xb, NN, mode2);
  }

  pool_kernel<<<(NN + 127) / 128, 128, 0, stream>>>(xb, batch, pooled);
  fc_kernel<<<NG, 128, 0, stream>>>(pooled, fc1_W, fc1_b, fc2_W, fc2_b, out);
}